// Round 1
// baseline (1117.900 us; speedup 1.0000x reference)
//
#include <hip/hip_runtime.h>

// FastGuidedFilter: 24 planes (8 batch x 3 chan) of 1024x1024 f32.
// r=8 (17x17 clipped box window). Fully fused single kernel, tile-based.
//
// Per output tile (TH x TW = 32 x 64):
//   raw x,y loaded with halo 16  -> 64 x 96 region in LDS (zero outside image)
//   box sums of {x,y,xy,xx} on tile+halo8 (48 x 80) via separable running scans
//   A,b on 48 x 80 (zero outside image)
//   box sums of {A,b} on tile (32 x 64)
//   out = (boxA/N)*x + boxb/N

#define HH 1024
#define WW 1024
#define NPLANES 24
#define RAD 8
#define TH 32
#define TW 64

#define RAWROWS (TH + 32)      // 64
#define RAWCOLS (TW + 32)      // 96
#define RAWSTR  (RAWCOLS + 1)  // 97  (odd stride -> conflict-free row-indexed scans)

#define HROWS RAWROWS          // 64
#define HCOLS (TW + 16)        // 80
#define HSTR  (HCOLS + 1)      // 81

#define BROWS (TH + 16)        // 48
#define STR2  (TW + 1)         // 65

// Region A: max(2*RAWROWS*RAWSTR, 4*BROWS*HSTR) = max(12416, 15552) = 15552 floats
// Region B: 4*HROWS*HSTR = 20736 floats
#define REGA 15552
#define REGB 20736
#define SMEM_FLOATS (REGA + REGB)
#define SMEM_BYTES  (SMEM_FLOATS * 4)   // 145152 B

extern "C" __global__ __launch_bounds__(256)
void fgf_fused(const float* __restrict__ x, const float* __restrict__ y,
               float* __restrict__ out)
{
    extern __shared__ float smem[];
    float* RA = smem;         // region A
    float* RB = smem + REGA;  // region B

    const int tid = threadIdx.x;
    const int tc = blockIdx.x;        // tile col index (0..15)
    const int tr = blockIdx.y;        // tile row index (0..31)
    const int p  = blockIdx.z;        // plane (0..23)
    const int R0 = tr * TH;
    const int C0 = tc * TW;
    const size_t planeOff = (size_t)p * HH * WW;
    const float* xp = x + planeOff;
    const float* yp = y + planeOff;
    float* op = out + planeOff;

    float* rawx = RA;
    float* rawy = RA + RAWROWS * RAWSTR;

    // ---- Phase 0: load raw x,y with halo 16, zero outside image ----
    for (int idx = tid; idx < RAWROWS * RAWCOLS; idx += 256) {
        int rr = idx / RAWCOLS;
        int cc = idx - rr * RAWCOLS;
        int gi = R0 - 16 + rr;
        int gj = C0 - 16 + cc;
        float vx = 0.f, vy = 0.f;
        if (gi >= 0 && gi < HH && gj >= 0 && gj < WW) {
            size_t g = (size_t)gi * WW + gj;
            vx = xp[g];
            vy = yp[g];
        }
        rawx[rr * RAWSTR + cc] = vx;
        rawy[rr * RAWSTR + cc] = vy;
    }
    __syncthreads();

    // ---- Phase H1: horizontal 17-wide running sums of {x,y,xy,xx} ----
    // 4 quantities x 64 rows = 256 threads. Output cols jj=0..79 (image col C0-8+jj),
    // window = raw cols [jj, jj+16].
    {
        const int q   = tid >> 6;   // wave-uniform
        const int row = tid & 63;
        const float* rx = rawx + row * RAWSTR;
        const float* ry = rawy + row * RAWSTR;
        float* hq = RB + (q * HROWS + row) * HSTR;

#define H1_SCAN(VAL_EXPR)                                    \
        {                                                    \
            float s = 0.f;                                   \
            for (int k = 0; k < 16; ++k) { int c = k; s += (VAL_EXPR); } \
            for (int j = 0; j < HCOLS; ++j) {                \
                { int c = j + 16; s += (VAL_EXPR); }         \
                hq[j] = s;                                   \
                { int c = j; s -= (VAL_EXPR); }              \
            }                                                \
        }
        if (q == 0)      H1_SCAN(rx[c])
        else if (q == 1) H1_SCAN(ry[c])
        else if (q == 2) H1_SCAN(rx[c] * ry[c])
        else             H1_SCAN(rx[c] * rx[c])
#undef H1_SCAN
    }
    __syncthreads();

    // ---- Phase V1: vertical 17-tall running sums -> box sums on 48x80 ----
    for (int item = tid; item < 4 * HCOLS; item += 256) {
        int q   = item / HCOLS;
        int col = item - q * HCOLS;
        const float* hq = RB + q * HROWS * HSTR + col;
        float* bq = RA + q * BROWS * HSTR + col;
        float s = 0.f;
        for (int k = 0; k < 16; ++k) s += hq[k * HSTR];
        for (int i = 0; i < BROWS; ++i) {
            s += hq[(i + 16) * HSTR];
            bq[i * HSTR] = s;
            s -= hq[i * HSTR];
        }
    }
    __syncthreads();

    // ---- Phase AB: per-pixel A,b on 48x80 (zero outside image) ----
    for (int it = tid; it < BROWS * HCOLS; it += 256) {
        int ii = it / HCOLS;
        int jj = it - ii * HCOLS;
        int gi = R0 - 8 + ii;
        int gj = C0 - 8 + jj;
        float Av = 0.f, bv = 0.f;
        if (gi >= 0 && gi < HH && gj >= 0 && gj < WW) {
            float cntR = (float)(min(gi + RAD, HH - 1) - max(gi - RAD, 0) + 1);
            float cntC = (float)(min(gj + RAD, WW - 1) - max(gj - RAD, 0) + 1);
            float invN = 1.f / (cntR * cntC);
            float sx  = RA[0 * BROWS * HSTR + ii * HSTR + jj];
            float sy  = RA[1 * BROWS * HSTR + ii * HSTR + jj];
            float sxy = RA[2 * BROWS * HSTR + ii * HSTR + jj];
            float sxx = RA[3 * BROWS * HSTR + ii * HSTR + jj];
            float mx  = sx * invN;
            float my  = sy * invN;
            float cov = sxy * invN - mx * my;
            float vr  = sxx * invN - mx * mx;
            Av = cov / (vr + 1e-8f);
            bv = my - Av * mx;
        }
        RB[ii * HSTR + jj] = Av;                        // A field (48x80, stride 81)
        RB[BROWS * HSTR + ii * HSTR + jj] = bv;         // b field
    }
    __syncthreads();

    // ---- Phase H2: horizontal running sums of {A,b} -> 48 x 64 ----
    if (tid < 2 * BROWS) {
        int q   = tid / BROWS;   // 0=A, 1=b
        int row = tid - q * BROWS;
        const float* src = RB + q * BROWS * HSTR + row * HSTR;
        float* dst = RA + (q * BROWS + row) * STR2;
        float s = 0.f;
        for (int k = 0; k < 16; ++k) s += src[k];
        for (int j = 0; j < TW; ++j) {
            s += src[j + 16];
            dst[j] = s;
            s -= src[j];
        }
    }
    __syncthreads();

    // ---- Phase V2: vertical running sums -> box{A,b} on 32 x 64 ----
    if (tid < 2 * TW) {
        int q   = tid >> 6;      // 0=A, 1=b
        int col = tid & 63;
        const float* src = RA + q * BROWS * STR2 + col;
        float* dst = RB + q * TH * STR2 + col;
        float s = 0.f;
        for (int k = 0; k < 16; ++k) s += src[k * STR2];
        for (int i = 0; i < TH; ++i) {
            s += src[(i + 16) * STR2];
            dst[i * STR2] = s;
            s -= src[i * STR2];
        }
    }
    __syncthreads();

    // ---- Final: out = (boxA/N) * x + boxb/N ----
    for (int it = tid; it < TH * TW; it += 256) {
        int ii = it >> 6;        // /64
        int jj = it & 63;
        int gi = R0 + ii;
        int gj = C0 + jj;
        float cntR = (float)(min(gi + RAD, HH - 1) - max(gi - RAD, 0) + 1);
        float cntC = (float)(min(gj + RAD, WW - 1) - max(gj - RAD, 0) + 1);
        float invN = 1.f / (cntR * cntC);
        float mA = RB[ii * STR2 + jj] * invN;
        float mb = RB[TH * STR2 + ii * STR2 + jj] * invN;
        size_t g = (size_t)gi * WW + gj;
        op[g] = mA * xp[g] + mb;
    }
}

extern "C" void kernel_launch(void* const* d_in, const int* in_sizes, int n_in,
                              void* d_out, int out_size, void* d_ws, size_t ws_size,
                              hipStream_t stream) {
    const float* x = (const float*)d_in[0];
    const float* y = (const float*)d_in[1];
    float* out = (float*)d_out;

    // Allow >64KB dynamic LDS (gfx950 has 160 KiB/CU). Cheap host-side call,
    // graph-capture safe (no stream op).
    hipFuncSetAttribute((const void*)fgf_fused,
                        hipFuncAttributeMaxDynamicSharedMemorySize, SMEM_BYTES);

    dim3 grid(WW / TW, HH / TH, NPLANES);
    fgf_fused<<<grid, 256, SMEM_BYTES, stream>>>(x, y, out);
}

// Round 2
// 422.106 us; speedup vs baseline: 2.6484x; 2.6484x over previous
//
#include <hip/hip_runtime.h>

// FastGuidedFilter: 24 planes (8x3) of 1024x1024 f32, r=8 (17x17 clipped box).
//
// Two-kernel pipeline through d_ws (A,b planes, 201 MB):
//   K1: per 32x32 tile (halo 8): box sums of {x,y,xy,xx} -> A,b -> ws
//   K2: per 32x32 tile (halo 8): box sums of {A,b} -> out = meanA*x + meanb
// Both keep LDS <= 44 KB so 3-5 blocks/CU are resident (vs 1 for the fused
// 145 KB version), and all scan phases keep 192-256 threads busy.
//
// Fallback: if ws_size < 201 MB, run the previous fused single kernel.

#define HH 1024
#define WW 1024
#define NPLANES 24
#define RAD 8

// ---------------- two-kernel pipeline (tile 32x32, halo 8) ----------------
#define TS 32
#define RW 48            // TS + 2*RAD
#define RSTR 49          // raw stride (odd -> conflict-free row reads)
#define HSTR2 33         // h-sum stride (32 cols + 1)

// K1 LDS: raw 2*48*49 = 4704 fl (18.8 KB), h 4*48*33 = 6336 fl (25.3 KB)
// box (4*32*33 = 4224 fl) overlaid on raw after it dies. Peak 44.2 KB.
__global__ __launch_bounds__(256)
void fgf_ab(const float* __restrict__ x, const float* __restrict__ y,
            float* __restrict__ Aw, float* __restrict__ bw)
{
    __shared__ float raw[2 * RW * RSTR];
    __shared__ float hsum[4 * RW * HSTR2];
    float* box = raw;  // overlay: 4*TS*HSTR2 = 4224 <= 4704

    const int tid = threadIdx.x;
    const int C0 = blockIdx.x * TS;
    const int R0 = blockIdx.y * TS;
    const int p  = blockIdx.z;
    const size_t po = (size_t)p * HH * WW;
    const float* xp = x + po;
    const float* yp = y + po;

    float* rawx = raw;
    float* rawy = raw + RW * RSTR;

    // load raw x,y with halo 8, zero outside image
    for (int idx = tid; idx < RW * RW; idx += 256) {
        int rr = idx / RW, cc = idx - rr * RW;
        int gi = R0 - RAD + rr, gj = C0 - RAD + cc;
        float vx = 0.f, vy = 0.f;
        if (gi >= 0 && gi < HH && gj >= 0 && gj < WW) {
            size_t g = (size_t)gi * WW + gj;
            vx = xp[g]; vy = yp[g];
        }
        rawx[rr * RSTR + cc] = vx;
        rawy[rr * RSTR + cc] = vy;
    }
    __syncthreads();

    // H: horizontal 17-wide running sums of {x,y,xy,xx}; 4 waves, one q each
    {
        const int q = tid >> 6;        // wave-uniform
        const int row = tid & 63;
        if (row < RW) {
            const float* rx = &rawx[row * RSTR];
            const float* ry = &rawy[row * RSTR];
            float* hq = &hsum[(q * RW + row) * HSTR2];
            float s = 0.f;
#define HSCAN(E) { for (int c = 0; c < 16; ++c) s += (E); \
                   for (int j = 0; j < TS; ++j) { int c = j + 16; s += (E); \
                     hq[j] = s; c = j; s -= (E); } }
            if (q == 0)      HSCAN(rx[c])
            else if (q == 1) HSCAN(ry[c])
            else if (q == 2) HSCAN(rx[c] * ry[c])
            else             HSCAN(rx[c] * rx[c])
#undef HSCAN
        }
    }
    __syncthreads();

    // V: vertical 17-tall running sums; 256 jobs = 4q x 32col x 2 half
    {
        const int col  = tid & 31;
        const int q    = (tid >> 5) & 3;
        const int half = tid >> 7;
        const float* hq = &hsum[q * RW * HSTR2 + col];
        float* bq = &box[q * TS * HSTR2 + col];
        const int i0 = half * 16;      // output rows i0..i0+15
        float s = 0.f;
        for (int k = 0; k < 16; ++k) s += hq[(i0 + k) * HSTR2];
        for (int i = i0; i < i0 + 16; ++i) {
            s += hq[(i + 16) * HSTR2];
            bq[i * HSTR2] = s;
            s -= hq[i * HSTR2];
        }
    }
    __syncthreads();

    // A,b per pixel -> global ws
    float* Ap = Aw + po;
    float* bp = bw + po;
    for (int idx = tid; idx < TS * TS; idx += 256) {
        int ii = idx >> 5, jj = idx & 31;
        int gi = R0 + ii, gj = C0 + jj;
        float cntR = (float)(min(gi + RAD, HH - 1) - max(gi - RAD, 0) + 1);
        float cntC = (float)(min(gj + RAD, WW - 1) - max(gj - RAD, 0) + 1);
        float invN = 1.f / (cntR * cntC);
        float sx  = box[(0 * TS + ii) * HSTR2 + jj];
        float sy  = box[(1 * TS + ii) * HSTR2 + jj];
        float sxy = box[(2 * TS + ii) * HSTR2 + jj];
        float sxx = box[(3 * TS + ii) * HSTR2 + jj];
        float mx = sx * invN, my = sy * invN;
        float cov = sxy * invN - mx * my;
        float vr  = sxx * invN - mx * mx;
        float A = cov / (vr + 1e-8f);
        float b = my - A * mx;
        size_t g = (size_t)gi * WW + gj;
        Ap[g] = A; bp[g] = b;
    }
}

// K2 LDS: raw 2*48*49 = 4704 fl, h 2*48*33 = 3168 fl, box overlay. 31.5 KB.
__global__ __launch_bounds__(256)
void fgf_out(const float* __restrict__ Aw, const float* __restrict__ bw,
             const float* __restrict__ x, float* __restrict__ out)
{
    __shared__ float raw[2 * RW * RSTR];
    __shared__ float hsum[2 * RW * HSTR2];
    float* box = raw;  // overlay: 2*TS*HSTR2 = 2112 <= 4704

    const int tid = threadIdx.x;
    const int C0 = blockIdx.x * TS;
    const int R0 = blockIdx.y * TS;
    const int p  = blockIdx.z;
    const size_t po = (size_t)p * HH * WW;
    const float* Apl = Aw + po;
    const float* bpl = bw + po;

    float* rawA = raw;
    float* rawB = raw + RW * RSTR;

    for (int idx = tid; idx < RW * RW; idx += 256) {
        int rr = idx / RW, cc = idx - rr * RW;
        int gi = R0 - RAD + rr, gj = C0 - RAD + cc;
        float vA = 0.f, vB = 0.f;
        if (gi >= 0 && gi < HH && gj >= 0 && gj < WW) {
            size_t g = (size_t)gi * WW + gj;
            vA = Apl[g]; vB = bpl[g];
        }
        rawA[rr * RSTR + cc] = vA;
        rawB[rr * RSTR + cc] = vB;
    }
    __syncthreads();

    // H: 2q x 48row x 2half = 192 jobs mapped on (tid>>6, tid&63)
    {
        const int g2 = tid >> 6;       // 0..3 : (q,half) = (g2>>1, g2&1)
        const int row = tid & 63;
        if (row < RW) {
            const int q = g2 >> 1, half = g2 & 1;
            const float* rq = &raw[q * RW * RSTR + row * RSTR];
            float* hq = &hsum[(q * RW + row) * HSTR2];
            const int j0 = half * 16;  // output cols j0..j0+15
            float s = 0.f;
            for (int c = j0; c < j0 + 16; ++c) s += rq[c];
            for (int j = j0; j < j0 + 16; ++j) {
                s += rq[j + 16];
                hq[j] = s;
                s -= rq[j];
            }
        }
    }
    __syncthreads();

    // V: 2q x 32col x 4quarter = 256 jobs
    {
        const int col = tid & 31;
        const int q   = (tid >> 5) & 1;
        const int qt  = tid >> 6;
        const float* hq = &hsum[q * RW * HSTR2 + col];
        float* bq = &box[q * TS * HSTR2 + col];
        const int i0 = qt * 8;
        float s = 0.f;
        for (int k = 0; k < 16; ++k) s += hq[(i0 + k) * HSTR2];
        for (int i = i0; i < i0 + 8; ++i) {
            s += hq[(i + 16) * HSTR2];
            bq[i * HSTR2] = s;
            s -= hq[i * HSTR2];
        }
    }
    __syncthreads();

    const float* xp = x + po;
    float* op = out + po;
    for (int idx = tid; idx < TS * TS; idx += 256) {
        int ii = idx >> 5, jj = idx & 31;
        int gi = R0 + ii, gj = C0 + jj;
        float cntR = (float)(min(gi + RAD, HH - 1) - max(gi - RAD, 0) + 1);
        float cntC = (float)(min(gj + RAD, WW - 1) - max(gj - RAD, 0) + 1);
        float invN = 1.f / (cntR * cntC);
        float mA = box[(0 * TS + ii) * HSTR2 + jj] * invN;
        float mb = box[(1 * TS + ii) * HSTR2 + jj] * invN;
        size_t g = (size_t)gi * WW + gj;
        op[g] = mA * xp[g] + mb;
    }
}

// ---------------- fallback: previous fused kernel (1 block/CU) ----------------
#define TH 32
#define TW 64
#define RAWROWS (TH + 32)
#define RAWCOLS (TW + 32)
#define RAWSTR  (RAWCOLS + 1)
#define HROWS RAWROWS
#define HCOLS (TW + 16)
#define FHSTR  (HCOLS + 1)
#define BROWS (TH + 16)
#define STR2  (TW + 1)
#define REGA 15552
#define REGB 20736
#define SMEM_FLOATS (REGA + REGB)
#define SMEM_BYTES  (SMEM_FLOATS * 4)

extern "C" __global__ __launch_bounds__(256)
void fgf_fused(const float* __restrict__ x, const float* __restrict__ y,
               float* __restrict__ out)
{
    extern __shared__ float smem[];
    float* RA = smem;
    float* RB = smem + REGA;

    const int tid = threadIdx.x;
    const int tc = blockIdx.x;
    const int tr = blockIdx.y;
    const int p  = blockIdx.z;
    const int R0 = tr * TH;
    const int C0 = tc * TW;
    const size_t planeOff = (size_t)p * HH * WW;
    const float* xp = x + planeOff;
    const float* yp = y + planeOff;
    float* op = out + planeOff;

    float* rawx = RA;
    float* rawy = RA + RAWROWS * RAWSTR;

    for (int idx = tid; idx < RAWROWS * RAWCOLS; idx += 256) {
        int rr = idx / RAWCOLS;
        int cc = idx - rr * RAWCOLS;
        int gi = R0 - 16 + rr;
        int gj = C0 - 16 + cc;
        float vx = 0.f, vy = 0.f;
        if (gi >= 0 && gi < HH && gj >= 0 && gj < WW) {
            size_t g = (size_t)gi * WW + gj;
            vx = xp[g]; vy = yp[g];
        }
        rawx[rr * RAWSTR + cc] = vx;
        rawy[rr * RAWSTR + cc] = vy;
    }
    __syncthreads();

    {
        const int q   = tid >> 6;
        const int row = tid & 63;
        const float* rx = rawx + row * RAWSTR;
        const float* ry = rawy + row * RAWSTR;
        float* hq = RB + (q * HROWS + row) * FHSTR;
#define H1_SCAN(VAL_EXPR)                                    \
        {                                                    \
            float s = 0.f;                                   \
            for (int k = 0; k < 16; ++k) { int c = k; s += (VAL_EXPR); } \
            for (int j = 0; j < HCOLS; ++j) {                \
                { int c = j + 16; s += (VAL_EXPR); }         \
                hq[j] = s;                                   \
                { int c = j; s -= (VAL_EXPR); }              \
            }                                                \
        }
        if (q == 0)      H1_SCAN(rx[c])
        else if (q == 1) H1_SCAN(ry[c])
        else if (q == 2) H1_SCAN(rx[c] * ry[c])
        else             H1_SCAN(rx[c] * rx[c])
#undef H1_SCAN
    }
    __syncthreads();

    for (int item = tid; item < 4 * HCOLS; item += 256) {
        int q   = item / HCOLS;
        int col = item - q * HCOLS;
        const float* hq = RB + q * HROWS * FHSTR + col;
        float* bq = RA + q * BROWS * FHSTR + col;
        float s = 0.f;
        for (int k = 0; k < 16; ++k) s += hq[k * FHSTR];
        for (int i = 0; i < BROWS; ++i) {
            s += hq[(i + 16) * FHSTR];
            bq[i * FHSTR] = s;
            s -= hq[i * FHSTR];
        }
    }
    __syncthreads();

    for (int it = tid; it < BROWS * HCOLS; it += 256) {
        int ii = it / HCOLS;
        int jj = it - ii * HCOLS;
        int gi = R0 - 8 + ii;
        int gj = C0 - 8 + jj;
        float Av = 0.f, bv = 0.f;
        if (gi >= 0 && gi < HH && gj >= 0 && gj < WW) {
            float cntR = (float)(min(gi + RAD, HH - 1) - max(gi - RAD, 0) + 1);
            float cntC = (float)(min(gj + RAD, WW - 1) - max(gj - RAD, 0) + 1);
            float invN = 1.f / (cntR * cntC);
            float sx  = RA[0 * BROWS * FHSTR + ii * FHSTR + jj];
            float sy  = RA[1 * BROWS * FHSTR + ii * FHSTR + jj];
            float sxy = RA[2 * BROWS * FHSTR + ii * FHSTR + jj];
            float sxx = RA[3 * BROWS * FHSTR + ii * FHSTR + jj];
            float mx  = sx * invN;
            float my  = sy * invN;
            float cov = sxy * invN - mx * my;
            float vr  = sxx * invN - mx * mx;
            Av = cov / (vr + 1e-8f);
            bv = my - Av * mx;
        }
        RB[ii * FHSTR + jj] = Av;
        RB[BROWS * FHSTR + ii * FHSTR + jj] = bv;
    }
    __syncthreads();

    if (tid < 2 * BROWS) {
        int q   = tid / BROWS;
        int row = tid - q * BROWS;
        const float* src = RB + q * BROWS * FHSTR + row * FHSTR;
        float* dst = RA + (q * BROWS + row) * STR2;
        float s = 0.f;
        for (int k = 0; k < 16; ++k) s += src[k];
        for (int j = 0; j < TW; ++j) {
            s += src[j + 16];
            dst[j] = s;
            s -= src[j];
        }
    }
    __syncthreads();

    if (tid < 2 * TW) {
        int q   = tid >> 6;
        int col = tid & 63;
        const float* src = RA + q * BROWS * STR2 + col;
        float* dst = RB + q * TH * STR2 + col;
        float s = 0.f;
        for (int k = 0; k < 16; ++k) s += src[k * STR2];
        for (int i = 0; i < TH; ++i) {
            s += src[(i + 16) * STR2];
            dst[i * STR2] = s;
            s -= src[i * STR2];
        }
    }
    __syncthreads();

    for (int it = tid; it < TH * TW; it += 256) {
        int ii = it >> 6;
        int jj = it & 63;
        int gi = R0 + ii;
        int gj = C0 + jj;
        float cntR = (float)(min(gi + RAD, HH - 1) - max(gi - RAD, 0) + 1);
        float cntC = (float)(min(gj + RAD, WW - 1) - max(gj - RAD, 0) + 1);
        float invN = 1.f / (cntR * cntC);
        float mA = RB[ii * STR2 + jj] * invN;
        float mb = RB[TH * STR2 + ii * STR2 + jj] * invN;
        size_t g = (size_t)gi * WW + gj;
        op[g] = mA * xp[g] + mb;
    }
}

extern "C" void kernel_launch(void* const* d_in, const int* in_sizes, int n_in,
                              void* d_out, int out_size, void* d_ws, size_t ws_size,
                              hipStream_t stream) {
    const float* x = (const float*)d_in[0];
    const float* y = (const float*)d_in[1];
    float* out = (float*)d_out;

    const size_t planeFloats = (size_t)NPLANES * HH * WW;   // 24M
    const size_t wsNeed = 2 * planeFloats * sizeof(float);  // 201.3 MB

    if (ws_size >= wsNeed) {
        float* Aw = (float*)d_ws;
        float* bw = Aw + planeFloats;
        dim3 grid(WW / TS, HH / TS, NPLANES);
        fgf_ab<<<grid, 256, 0, stream>>>(x, y, Aw, bw);
        fgf_out<<<grid, 256, 0, stream>>>(Aw, bw, x, out);
    } else {
        hipFuncSetAttribute((const void*)fgf_fused,
                            hipFuncAttributeMaxDynamicSharedMemorySize, SMEM_BYTES);
        dim3 grid(WW / TW, HH / TH, NPLANES);
        fgf_fused<<<grid, 256, SMEM_BYTES, stream>>>(x, y, out);
    }
}